// Round 7
// baseline (881.127 us; speedup 1.0000x reference)
//
#include <hip/hip_runtime.h>
#include <math.h>

#define N_MEM 100000
#define NP    100352      // 49 * 2048 (padded)
#define NCH   49
#define CHUNK 2048
#define QCAP  768         // per-query survivor buffer (expected ~390)
#define NCAND 64          // max re-rank set size

__device__ __forceinline__ float softplusf_(float x){ return log1pf(expf(x)); }

__device__ __forceinline__ double wave_sum_d(double v){
  #pragma unroll
  for (int o=32;o;o>>=1) v += __shfl_xor(v, o, 64);
  return v;
}

// argmax carrying (value, global-index tie-break, position meta)
__device__ __forceinline__ void wave_argmax3(float& v, int& j, int& p){
  #pragma unroll
  for (int o=32;o;o>>=1){
    float ov = __shfl_xor(v, o, 64);
    int   oj = __shfl_xor(j, o, 64);
    int   op = __shfl_xor(p, o, 64);
    if (ov > v || (ov == v && oj < j)) { v = ov; j = oj; p = op; }
  }
}

// ---------------- K1: memory embeddings -> mwT (64 x NP), mm  (fp32 stream path)
__global__ __launch_bounds__(128) void k1_mem(
    const float* __restrict__ mi,
    const float* __restrict__ w1, const float* __restrict__ b1,
    const float* __restrict__ w2, const float* __restrict__ b2,
    const float* __restrict__ fw,
    float* __restrict__ mwT, float* __restrict__ mm)
{
  __shared__ float xs[64*128];
  int t = threadIdx.x;
  int j = blockIdx.x*128 + t;
  bool real = (j < N_MEM);
  {
    const float4* xp = (const float4*)(mi + (size_t)(real ? j : 0)*64);
    #pragma unroll
    for (int k=0;k<16;k++){
      float4 v = xp[k];
      xs[(4*k+0)*128 + t] = v.x;
      xs[(4*k+1)*128 + t] = v.y;
      xs[(4*k+2)*128 + t] = v.z;
      xs[(4*k+3)*128 + t] = v.w;
    }
  }
  float h[64];
  #pragma unroll
  for (int e=0;e<64;e++) h[e] = b1[e];
  for (int d=0; d<64; d++){
    float xv = xs[d*128 + t];
    #pragma unroll
    for (int e=0;e<64;e++) h[e] = fmaf(xv, w1[d*64+e], h[e]);
  }
  #pragma unroll
  for (int e=0;e<64;e++){ h[e] = fmaxf(h[e], 0.f); xs[e*128 + t] = h[e]; }
  float o[64];
  #pragma unroll
  for (int e=0;e<64;e++) o[e] = b2[e];
  for (int d=0; d<64; d++){
    float hv = xs[d*128 + t];
    #pragma unroll
    for (int e=0;e<64;e++) o[e] = fmaf(hv, w2[d*64+e], o[e]);
  }
  float s2 = 0.f;
  #pragma unroll
  for (int e=0;e<64;e++){
    float sw = sqrtf(softplusf_(fw[e]) + 1e-9f);
    float v = real ? o[e]*sw : 0.f;
    s2 = fmaf(v, v, s2);
    mwT[(size_t)e*NP + j] = v;
  }
  mm[j] = real ? s2 : 3.0e38f;
}

// ---------------- K2: per-query: f64 local embedding + global path + gate; zero qcnt
__global__ __launch_bounds__(64) void k2_query(
  const float* __restrict__ x,
  const float* __restrict__ le_w1, const float* __restrict__ le_b1,
  const float* __restrict__ le_w2, const float* __restrict__ le_b2,
  const float* __restrict__ fw,
  const float* __restrict__ ge_w1, const float* __restrict__ ge_b1,
  const float* __restrict__ ge_w2, const float* __restrict__ ge_b2,
  const float* __restrict__ ge_w3, const float* __restrict__ ge_b3,
  const float* __restrict__ gr_w1, const float* __restrict__ gr_b1,
  const float* __restrict__ gr_w2, const float* __restrict__ gr_b2,
  const float* __restrict__ ga_w1, const float* __restrict__ ga_b1,
  const float* __restrict__ ga_w2, const float* __restrict__ ga_b2,
  float* __restrict__ qwf, double* __restrict__ qwd,
  double* __restrict__ qqd, double* __restrict__ ggd, double* __restrict__ gpd,
  int* __restrict__ qcnt)
{
  int l = threadIdx.x, q = blockIdx.x;
  if (l==0) qcnt[q] = 0;
  __shared__ double xs[64], qe[64], h1[128], t1[64], t2[64];
  xs[l] = (double)x[q*64+l];
  __syncthreads();
  double a = (double)le_b1[l];
  for (int d=0; d<64; d++) a = fma(xs[d], (double)le_w1[d*64+l], a);
  t1[l] = a > 0.0 ? a : 0.0;
  __syncthreads();
  a = (double)le_b2[l];
  for (int d=0; d<64; d++) a = fma(t1[d], (double)le_w2[d*64+l], a);
  qe[l] = a;
  double sw = sqrt(log1p(exp((double)fw[l])) + 1e-9);
  double qv = a * sw;
  qwd[q*64+l] = qv;
  qwf[q*64+l] = (float)qv;
  double ss = wave_sum_d(qv*qv);
  if (l==0) qqd[q] = ss;
  // ge layer1 (128 wide)
  double a0 = (double)ge_b1[l], a1 = (double)ge_b1[64+l];
  for (int d=0; d<64; d++){
    double xv = xs[d];
    a0 = fma(xv, (double)ge_w1[d*128+l],    a0);
    a1 = fma(xv, (double)ge_w1[d*128+64+l], a1);
  }
  h1[l] = a0>0.0?a0:0.0; h1[64+l] = a1>0.0?a1:0.0;
  __syncthreads();
  a = (double)ge_b2[l];
  for (int d=0; d<128; d++) a = fma(h1[d], (double)ge_w2[d*64+l], a);
  __syncthreads();
  t1[l] = a>0.0?a:0.0;
  __syncthreads();
  a = (double)ge_b3[l];
  for (int d=0; d<64; d++) a = fma(t1[d], (double)ge_w3[d*64+l], a);
  t2[l] = a;                // global_repr
  __syncthreads();
  a = (double)gr_b1[l];
  for (int d=0; d<64; d++) a = fma(t2[d], (double)gr_w1[d*64+l], a);
  __syncthreads();
  t1[l] = a>0.0?a:0.0;
  __syncthreads();
  if (l < 8){
    double b = (double)gr_b2[l];
    for (int d=0; d<64; d++) b = fma(t1[d], (double)gr_w2[d*8+l], b);
    gpd[q*8+l] = b;
  }
  a = (double)ga_b1[l];
  for (int d=0; d<64; d++) a = fma(t2[d], (double)ga_w1[d*64+l], a);
  for (int d=0; d<64; d++) a = fma(qe[d], (double)ga_w1[(64+d)*64+l], a);
  a = a>0.0?a:0.0;
  double p = wave_sum_d(a * (double)ga_w2[l]);
  if (l==0) ggd[q] = 1.0/(1.0 + exp(-(p + (double)ga_b2[0])));
}

// ---------------- K_tau_a: exact fp32 top-16 per (query, 512-subchunk), j in [0,4096)
__global__ __launch_bounds__(256) void k_tau_a(
    const float* __restrict__ mwT, const float* __restrict__ mm,
    const float* __restrict__ qw,
    float* __restrict__ tpv, int* __restrict__ tpi)
{
  int t = threadIdx.x, w = t>>6, lane = t&63;
  int q0 = blockIdx.x*32;
  int jb = blockIdx.y*512;
  __shared__ float qs[2048];
  for (int i=t; i<2048; i+=256){
    int qrel = i>>6, d = i&63;
    qs[(qrel>>3)*512 + d*8 + (qrel&7)] = qw[q0*64 + i];
  }
  __syncthreads();
  float s[8][8];
  #pragma unroll
  for (int a=0;a<8;a++){
    #pragma unroll
    for (int b=0;b<8;b++) s[a][b]=0.f;
  }
  #pragma unroll 4
  for (int d=0; d<64; d++){
    const float* row = mwT + (size_t)d*NP + jb + 4*lane;
    float4 m0 = *(const float4*)row;
    float4 m1 = *(const float4*)(row + 256);
    const float* qp = qs + w*512 + d*8;
    float4 qA = *(const float4*)qp;
    float4 qB = *(const float4*)(qp+4);
    float qvv[8] = {qA.x,qA.y,qA.z,qA.w,qB.x,qB.y,qB.z,qB.w};
    float mvv[8] = {m0.x,m0.y,m0.z,m0.w,m1.x,m1.y,m1.z,m1.w};
    #pragma unroll
    for (int qi=0;qi<8;qi++){
      #pragma unroll
      for (int jj=0;jj<8;jj++) s[qi][jj] = fmaf(qvv[qi], mvv[jj], s[qi][jj]);
    }
  }
  float4 mmA = *(const float4*)(mm + jb + 4*lane);
  float4 mmB = *(const float4*)(mm + jb + 256 + 4*lane);
  float mmv[8] = {mmA.x,mmA.y,mmA.z,mmA.w,mmB.x,mmB.y,mmB.z,mmB.w};
  for (int qi=0; qi<8; qi++){
    float sc[8];
    #pragma unroll
    for (int jj=0;jj<8;jj++) sc[jj] = 2.f*s[qi][jj] - mmv[jj];
    unsigned used = 0u;
    for (int it=0; it<16; it++){
      float v = -3.0e38f; int slot = 0; int jwin = jb + 4*lane;
      #pragma unroll
      for (int jj=0;jj<8;jj++){
        bool ok = !((used>>jj)&1u);
        int jg = jb + ((jj<4)? (4*lane+jj) : (256+4*lane+jj-4));
        if (ok && sc[jj] > v){ v = sc[jj]; slot = jj; jwin = jg; }
      }
      float rv = v; int rj = jwin; int rp = lane*8 + slot;
      wave_argmax3(rv, rj, rp);
      if ((rp>>3) == lane) used |= 1u << (rp&7);
      if (lane == it){
        int o = (q0 + w*8 + qi)*128 + blockIdx.y*16 + it;
        tpv[o] = rv; tpi[o] = rj;
      }
    }
  }
}

// ---------------- K_tau_b: tau = 16th of 4096-sample; append chunks-0/1 survivors
__global__ __launch_bounds__(64) void k_tau_b(
    const float* __restrict__ tpv, const int* __restrict__ tpi,
    float* __restrict__ tau,
    int* __restrict__ qcnt, float* __restrict__ qcv, int* __restrict__ qci)
{
  int l = threadIdx.x, q = blockIdx.x;
  float v0 = tpv[q*128 + l];      int i0 = tpi[q*128 + l];
  float v1 = tpv[q*128 + 64 + l]; int i1 = tpi[q*128 + 64 + l];
  __shared__ float sv0[17], sv1[17];
  __shared__ int   si0[16], si1[16];
  __shared__ float tau_s;
  if (l==0){ sv0[16] = -3.0e38f; sv1[16] = -3.0e38f; }
  bool u0=false, u1=false;
  for (int it=0; it<16; it++){
    float a = u0 ? -3.0e38f : v0; int aj = i0; int ap = l;
    wave_argmax3(a, aj, ap);
    if (ap == l) u0 = true;
    if (l == it){ sv0[it] = a; si0[it] = aj; }
  }
  for (int it=0; it<16; it++){
    float a = u1 ? -3.0e38f : v1; int aj = i1; int ap = l;
    wave_argmax3(a, aj, ap);
    if (ap == l) u1 = true;
    if (l == it){ sv1[it] = a; si1[it] = aj; }
  }
  __syncthreads();
  if (l==0){
    int a=0,b=0; float val = -3.0e38f;
    for (int k=0;k<16;k++){ val = (sv0[a] >= sv1[b]) ? sv0[a++] : sv1[b++]; }
    tau[q] = val; tau_s = val;
  }
  __syncthreads();
  float thr = tau_s - 5e-6f;
  if (l < 16){
    if (sv0[l] >= thr){
      int p = atomicAdd(&qcnt[q], 1);
      if (p < QCAP){ qcv[(size_t)q*QCAP+p] = sv0[l]; qci[(size_t)q*QCAP+p] = si0[l]; }
    }
    if (sv1[l] >= thr){
      int p = atomicAdd(&qcnt[q], 1);
      if (p < QCAP){ qcv[(size_t)q*QCAP+p] = sv1[l]; qci[(size_t)q*QCAP+p] = si1[l]; }
    }
  }
}

// ---------------- K3: chunks 2..48, filter >= tau - margin, append to global buffer
__global__ __launch_bounds__(256) void k3_main(
    const float* __restrict__ mwT, const float* __restrict__ mm,
    const float* __restrict__ qw,  const float* __restrict__ tau,
    int* __restrict__ qcnt, float* __restrict__ qcv, int* __restrict__ qci)
{
  int t=threadIdx.x, w=t>>6, lane=t&63;
  int q0 = blockIdx.x*32;
  int c  = blockIdx.y + 2;
  __shared__ float qs[2048];
  __shared__ float taus[32];
  for (int i=t; i<2048; i+=256){
    int qrel=i>>6, d=i&63;
    qs[(qrel>>3)*512 + d*8 + (qrel&7)] = qw[q0*64 + i];
  }
  if (t < 32){ taus[t]=tau[q0+t] - 5e-6f; }   // margin covers fp32 stream noise
  __syncthreads();
  for (int sub=0; sub<4; sub++){
    int jb = c*CHUNK + sub*512;
    float s[8][8];
    #pragma unroll
    for (int a=0;a<8;a++){
      #pragma unroll
      for (int b=0;b<8;b++) s[a][b]=0.f;
    }
    #pragma unroll 4
    for (int d=0; d<64; d++){
      const float* row = mwT + (size_t)d*NP + jb + 4*lane;
      float4 m0 = *(const float4*)row;
      float4 m1 = *(const float4*)(row + 256);
      const float* qp = qs + w*512 + d*8;
      float4 qA = *(const float4*)qp;
      float4 qB = *(const float4*)(qp+4);
      float qvv[8] = {qA.x,qA.y,qA.z,qA.w,qB.x,qB.y,qB.z,qB.w};
      float mvv[8] = {m0.x,m0.y,m0.z,m0.w,m1.x,m1.y,m1.z,m1.w};
      #pragma unroll
      for (int qi=0;qi<8;qi++){
        #pragma unroll
        for (int jj=0;jj<8;jj++) s[qi][jj] = fmaf(qvv[qi], mvv[jj], s[qi][jj]);
      }
    }
    float4 mmA = *(const float4*)(mm + jb + 4*lane);
    float4 mmB = *(const float4*)(mm + jb + 256 + 4*lane);
    float mmv[8] = {mmA.x,mmA.y,mmA.z,mmA.w,mmB.x,mmB.y,mmB.z,mmB.w};
    #pragma unroll
    for (int qi=0;qi<8;qi++){
      float tq = taus[w*8+qi];
      int qg = q0 + w*8 + qi;
      #pragma unroll
      for (int jj=0;jj<8;jj++){
        float sc = 2.f*s[qi][jj] - mmv[jj];
        if (sc >= tq){
          int p = atomicAdd(&qcnt[qg], 1);
          if (p < QCAP){
            qcv[(size_t)qg*QCAP+p] = sc;
            qci[(size_t)qg*QCAP+p] = jb + ((jj<4)?(4*lane+jj):(256+4*lane+jj-4));
          }
        }
      }
    }
  }
}

// ---------------- K4: v16 over survivor buffer -> threshold compaction ->
// multi-wave f64 re-rank -> f32-quantized select -> softmax/blend/refine
__global__ __launch_bounds__(256) void k4_final(
    const int* __restrict__ qcnt, const float* __restrict__ qcv, const int* __restrict__ qci,
    const double* __restrict__ qwd_g, const double* __restrict__ qqd_g,
    const double* __restrict__ ggd_g, const double* __restrict__ gpd_g,
    const float* __restrict__ mi, const float* __restrict__ mt,
    const float* __restrict__ le_w1, const float* __restrict__ le_b1,
    const float* __restrict__ le_w2, const float* __restrict__ le_b2,
    const float* __restrict__ fw, const float* __restrict__ itp,
    const float* __restrict__ rw1, const float* __restrict__ rb1,
    const float* __restrict__ rw2, const float* __restrict__ rb2,
    float* __restrict__ out)
{
  int t = threadIdx.x, w = t>>6, l = t&63, q = blockIdx.x;
  __shared__ float  svv[QCAP];
  __shared__ int    sii[QCAP];
  __shared__ float  v16s;
  __shared__ int    ncnt2;
  __shared__ int    candj[NCAND];
  __shared__ double cd2[NCAND];
  __shared__ double mdw[4][64], hdw[4][64];
  __shared__ float  selr[16];
  __shared__ int    selj[16];
  __shared__ double hh[32];
  int NC = qcnt[q]; NC = NC < QCAP ? NC : QCAP;
  // Phase A: load survivors
  for (int i=t; i<NC; i+=256){ svv[i]=qcv[(size_t)q*QCAP+i]; sii[i]=qci[(size_t)q*QCAP+i]; }
  if (t==0) ncnt2 = 0;
  __syncthreads();
  // Phase B (wave 0): v16 = 16th-largest stream score over survivors
  if (t < 64){
    unsigned m = 0u;
    float last = -3.0e38f;
    for (int it=0; it<16; it++){
      float bv = -3.0e38f; int bj = 0x7fffffff; int bp = 0;
      for (int k=0; k*64+l < NC; k++){
        if (!((m>>k)&1u)){
          float xv = svv[k*64+l]; int xj = sii[k*64+l];
          if (xv > bv || (xv == bv && xj < bj)){ bv=xv; bj=xj; bp=k*64+l; }
        }
      }
      wave_argmax3(bv, bj, bp);
      if ((bp&63) == l) m |= 1u << (bp>>6);
      last = bv;
    }
    if (l==0) v16s = last;
  }
  __syncthreads();
  // Phase C: threshold compaction (order-independent final result)
  {
    float thr = v16s - 1e-5f;
    for (int i=t; i<NC; i+=256){
      if (svv[i] >= thr && (unsigned)sii[i] < (unsigned)N_MEM){
        int p = atomicAdd(&ncnt2, 1);
        if (p < NCAND) candj[p] = sii[i];
      }
    }
  }
  __syncthreads();
  int NC2 = ncnt2 < NCAND ? ncnt2 : NCAND;
  // Phase D: f64 re-rank, candidates distributed across the 4 waves
  double qwl = qwd_g[q*64+l];
  double swl = sqrt(log1p(exp((double)fw[l])) + 1e-9);
  double qq  = qqd_g[q];
  int CM = (NC2 + 3) >> 2;
  for (int it=0; it<CM; it++){
    int c = it*4 + w;
    bool act = (c < NC2);
    if (act){
      int j = candj[c];
      mdw[w][l] = (double)mi[(size_t)j*64 + l];
    }
    __syncthreads();
    if (act){
      double a0=0,a1=0,a2=0,a3=0;
      for (int d=0; d<64; d+=4){
        a0 = fma(mdw[w][d  ], (double)le_w1[(d  )*64+l], a0);
        a1 = fma(mdw[w][d+1], (double)le_w1[(d+1)*64+l], a1);
        a2 = fma(mdw[w][d+2], (double)le_w1[(d+2)*64+l], a2);
        a3 = fma(mdw[w][d+3], (double)le_w1[(d+3)*64+l], a3);
      }
      double h = (a0+a1)+(a2+a3) + (double)le_b1[l];
      hdw[w][l] = h>0.0 ? h : 0.0;
    }
    __syncthreads();
    if (act){
      double a0=0,a1=0,a2=0,a3=0;
      for (int d=0; d<64; d+=4){
        a0 = fma(hdw[w][d  ], (double)le_w2[(d  )*64+l], a0);
        a1 = fma(hdw[w][d+1], (double)le_w2[(d+1)*64+l], a1);
        a2 = fma(hdw[w][d+2], (double)le_w2[(d+2)*64+l], a2);
        a3 = fma(hdw[w][d+3], (double)le_w2[(d+3)*64+l], a3);
      }
      double o  = (a0+a1)+(a2+a3) + (double)le_b2[l];
      double mw = o * swl;
      double mm2 = wave_sum_d(mw*mw);
      double dt  = wave_sum_d(mw*qwl);
      if (l==0) cd2[c] = qq + mm2 - 2.0*dt;
    }
    __syncthreads();
  }
  // Phase E (wave 0): f32-quantized raw + top-16 by (raw32 desc, idx asc)
  if (t < 64){
    float e32  = (float)exp((double)itp[0]);
    float sp32 = (float)log1p((double)e32);
    float t32  = __fadd_rn(sp32, 1e-9f);      // temp = softplus + EPS
    float dn32 = __fadd_rn(t32, 1e-9f);       // denom = temp + EPS
    double denom = (double)dn32;
    float rme; int jme;
    if (l < NC2){
      double d2 = cd2[l]; if (d2 < 0.0) d2 = 0.0;
      float ratio32 = (float)(d2 / denom);
      rme = (float)exp(-(double)ratio32);
      jme = candj[l];
    } else { rme = -2.0f; jme = 0x7fffffff; }
    bool used = false;
    for (int it=0; it<16; it++){
      float a = used ? -2.0f : rme; int aj = jme; int ap = l;
      wave_argmax3(a, aj, ap);
      if (ap == l) used = true;
      if (l == it){ selr[it]=a; selj[it]=aj; }
    }
  }
  __syncthreads();
  // Phase F (wave 0): f64 softmax over quantized raws, gather, blend, refine
  if (t < 64){
    double raw = (l<16) ? (double)selr[l] : -1.0e300;
    double mv = raw;
    #pragma unroll
    for (int o=32;o;o>>=1){ double ov = __shfl_xor(mv,o,64); mv = ov>mv?ov:mv; }
    double e  = (l<16) ? exp(raw - mv) : 0.0;
    double se = wave_sum_d(e);
    double wgt = e / se;
    double lp[8] = {0,0,0,0,0,0,0,0};
    if (l < 16){
      const float* tr = mt + (size_t)selj[l]*8;
      #pragma unroll
      for (int tt=0; tt<8; tt++) lp[tt] = wgt * (double)tr[tt];
    }
    #pragma unroll
    for (int tt=0; tt<8; tt++) lp[tt] = wave_sum_d(lp[tt]);
    double g = ggd_g[q];
    double bl[8];
    #pragma unroll
    for (int tt=0; tt<8; tt++) bl[tt] = g*lp[tt] + (1.0-g)*gpd_g[q*8+tt];
    if (l < 32){
      double a = (double)rb1[l];
      #pragma unroll
      for (int tt=0; tt<8; tt++) a = fma(bl[tt], (double)rw1[tt*32+l], a);
      hh[l] = a>0.0?a:0.0;
    }
  }
  __syncthreads();
  if (t < 8){
    double a = (double)rb2[t];
    #pragma unroll
    for (int i=0; i<32; i++) a = fma(hh[i], (double)rw2[i*8+t], a);
    out[q*8+t] = (float)a;
  }
}

extern "C" void kernel_launch(void* const* d_in, const int* in_sizes, int n_in,
                              void* d_out, int out_size, void* d_ws, size_t ws_size,
                              hipStream_t stream)
{
  const float* x     = (const float*)d_in[0];
  const float* mi    = (const float*)d_in[1];
  const float* mt    = (const float*)d_in[2];
  const float* le_w1 = (const float*)d_in[3];
  const float* le_b1 = (const float*)d_in[4];
  const float* le_w2 = (const float*)d_in[5];
  const float* le_b2 = (const float*)d_in[6];
  const float* fw    = (const float*)d_in[7];
  const float* itp   = (const float*)d_in[8];
  const float* ge_w1 = (const float*)d_in[9];
  const float* ge_b1 = (const float*)d_in[10];
  const float* ge_w2 = (const float*)d_in[11];
  const float* ge_b2 = (const float*)d_in[12];
  const float* ge_w3 = (const float*)d_in[13];
  const float* ge_b3 = (const float*)d_in[14];
  const float* gr_w1 = (const float*)d_in[15];
  const float* gr_b1 = (const float*)d_in[16];
  const float* gr_w2 = (const float*)d_in[17];
  const float* gr_b2 = (const float*)d_in[18];
  const float* ga_w1 = (const float*)d_in[19];
  const float* ga_b1 = (const float*)d_in[20];
  const float* ga_w2 = (const float*)d_in[21];
  const float* ga_b2 = (const float*)d_in[22];
  const float* rh_w1 = (const float*)d_in[23];
  const float* rh_b1 = (const float*)d_in[24];
  const float* rh_w2 = (const float*)d_in[25];
  const float* rh_b2 = (const float*)d_in[26];

  // doubles first (8B alignment), then float/int region
  double* dws = (double*)d_ws;
  double* qwd = dws;                                // 1024*64
  double* qqd = qwd + (size_t)1024*64;              // 1024
  double* ggd = qqd + 1024;                         // 1024
  double* gpd = ggd + 1024;                         // 8192
  float*  fws = (float*)(gpd + 8192);
  float* mwT = fws;                                 // 64*NP
  float* mm  = mwT + (size_t)64*NP;                 // NP
  float* qwf = mm  + NP;                            // 1024*64
  float* tau = qwf + (size_t)1024*64;               // 1024
  float* tpv = tau + 1024;                          // 1024*128
  int*   tpi = (int*)(tpv + (size_t)1024*128);      // 1024*128
  int*   qcnt= tpi + (size_t)1024*128;              // 1024
  float* qcv = (float*)(qcnt + 1024);               // 1024*QCAP
  int*   qci = (int*)(qcv + (size_t)1024*QCAP);     // 1024*QCAP

  k1_mem   <<<dim3(NP/128), dim3(128), 0, stream>>>(mi, le_w1, le_b1, le_w2, le_b2, fw, mwT, mm);
  k2_query <<<dim3(1024),   dim3(64),  0, stream>>>(x, le_w1, le_b1, le_w2, le_b2, fw,
                ge_w1, ge_b1, ge_w2, ge_b2, ge_w3, ge_b3,
                gr_w1, gr_b1, gr_w2, gr_b2,
                ga_w1, ga_b1, ga_w2, ga_b2,
                qwf, qwd, qqd, ggd, gpd, qcnt);
  k_tau_a  <<<dim3(32,8),   dim3(256), 0, stream>>>(mwT, mm, qwf, tpv, tpi);
  k_tau_b  <<<dim3(1024),   dim3(64),  0, stream>>>(tpv, tpi, tau, qcnt, qcv, qci);
  k3_main  <<<dim3(32,47),  dim3(256), 0, stream>>>(mwT, mm, qwf, tau, qcnt, qcv, qci);
  k4_final <<<dim3(1024),   dim3(256), 0, stream>>>(qcnt, qcv, qci, qwd, qqd, ggd, gpd, mi, mt,
                le_w1, le_b1, le_w2, le_b2, fw, itp,
                rh_w1, rh_b1, rh_w2, rh_b2, (float*)d_out);
}

// Round 9
// 715.446 us; speedup vs baseline: 1.2316x; 1.2316x over previous
//
#include <hip/hip_runtime.h>
#include <math.h>

#define N_MEM 100000
#define NP    100352      // 98 * 1024 (padded)
#define JBLK  1024
#define NJB   98
#define QCAP  1024        // per-query survivor buffer (expected ~390)
#define NCAND 128         // max re-rank set size

__device__ __forceinline__ float softplusf_(float x){ return log1pf(expf(x)); }

__device__ __forceinline__ double wave_sum_d(double v){
  #pragma unroll
  for (int o=32;o;o>>=1) v += __shfl_xor(v, o, 64);
  return v;
}
__device__ __forceinline__ int wave_sum_i(int v){
  #pragma unroll
  for (int o=32;o;o>>=1) v += __shfl_xor(v, o, 64);
  return v;
}

// argmax carrying (value, global-index tie-break, position meta)
__device__ __forceinline__ void wave_argmax3(float& v, int& j, int& p){
  #pragma unroll
  for (int o=32;o;o>>=1){
    float ov = __shfl_xor(v, o, 64);
    int   oj = __shfl_xor(j, o, 64);
    int   op = __shfl_xor(p, o, 64);
    if (ov > v || (ov == v && oj < j)) { v = ov; j = oj; p = op; }
  }
}

// full ascending bitonic sort of one value/lane across 64 lanes; lane 48 = 16th-largest
__device__ __forceinline__ float bitonic_sort64(float v, int lane){
  #pragma unroll
  for (int k=2;k<=64;k<<=1){
    #pragma unroll
    for (int j=k>>1;j>0;j>>=1){
      float o = __shfl_xor(v, j, 64);
      float mn = fminf(v,o), mx = fmaxf(v,o);
      bool upper = (lane & j) != 0;
      bool asc   = ((lane & k) == 0);
      v = (upper == asc) ? mx : mn;
    }
  }
  return v;
}

// ---------------- K1: memory embeddings -> mwT (64 x NP), mm (fp32 stream path)
__global__ __launch_bounds__(128) void k1_mem(
    const float* __restrict__ mi,
    const float* __restrict__ w1, const float* __restrict__ b1,
    const float* __restrict__ w2, const float* __restrict__ b2,
    const float* __restrict__ fw,
    float* __restrict__ mwT, float* __restrict__ mm)
{
  __shared__ float xs[64*128];
  int t = threadIdx.x;
  int j = blockIdx.x*128 + t;
  bool real = (j < N_MEM);
  {
    const float4* xp = (const float4*)(mi + (size_t)(real ? j : 0)*64);
    #pragma unroll
    for (int k=0;k<16;k++){
      float4 v = xp[k];
      xs[(4*k+0)*128 + t] = v.x;
      xs[(4*k+1)*128 + t] = v.y;
      xs[(4*k+2)*128 + t] = v.z;
      xs[(4*k+3)*128 + t] = v.w;
    }
  }
  float h[64];
  #pragma unroll
  for (int e=0;e<64;e++) h[e] = b1[e];
  for (int d=0; d<64; d++){
    float xv = xs[d*128 + t];
    #pragma unroll
    for (int e=0;e<64;e++) h[e] = fmaf(xv, w1[d*64+e], h[e]);
  }
  #pragma unroll
  for (int e=0;e<64;e++){ h[e] = fmaxf(h[e], 0.f); xs[e*128 + t] = h[e]; }
  float o[64];
  #pragma unroll
  for (int e=0;e<64;e++) o[e] = b2[e];
  for (int d=0; d<64; d++){
    float hv = xs[d*128 + t];
    #pragma unroll
    for (int e=0;e<64;e++) o[e] = fmaf(hv, w2[d*64+e], o[e]);
  }
  float s2 = 0.f;
  #pragma unroll
  for (int e=0;e<64;e++){
    float sw = sqrtf(softplusf_(fw[e]) + 1e-9f);
    float v = real ? o[e]*sw : 0.f;
    s2 = fmaf(v, v, s2);
    mwT[(size_t)e*NP + j] = v;
  }
  mm[j] = real ? s2 : 3.0e38f;
}

// ---------------- K2: per-query f64 embedding/global/gate (ILP-4 chains); zero qcnt
__global__ __launch_bounds__(64) void k2_query(
  const float* __restrict__ x,
  const float* __restrict__ le_w1, const float* __restrict__ le_b1,
  const float* __restrict__ le_w2, const float* __restrict__ le_b2,
  const float* __restrict__ fw,
  const float* __restrict__ ge_w1, const float* __restrict__ ge_b1,
  const float* __restrict__ ge_w2, const float* __restrict__ ge_b2,
  const float* __restrict__ ge_w3, const float* __restrict__ ge_b3,
  const float* __restrict__ gr_w1, const float* __restrict__ gr_b1,
  const float* __restrict__ gr_w2, const float* __restrict__ gr_b2,
  const float* __restrict__ ga_w1, const float* __restrict__ ga_b1,
  const float* __restrict__ ga_w2, const float* __restrict__ ga_b2,
  float* __restrict__ qwf, double* __restrict__ qwd,
  double* __restrict__ qqd, double* __restrict__ ggd, double* __restrict__ gpd,
  int* __restrict__ qcnt)
{
  int l = threadIdx.x, q = blockIdx.x;
  if (l==0) qcnt[q] = 0;
  __shared__ double xs[64], qe[64], h1[128], t1[64], t2[64];
  xs[l] = (double)x[q*64+l];
  __syncthreads();
  double a0,a1,a2,a3,a;
  // le1
  a0=a1=a2=a3=0.0;
  for (int d=0; d<64; d+=4){
    a0 = fma(xs[d  ], (double)le_w1[(d  )*64+l], a0);
    a1 = fma(xs[d+1], (double)le_w1[(d+1)*64+l], a1);
    a2 = fma(xs[d+2], (double)le_w1[(d+2)*64+l], a2);
    a3 = fma(xs[d+3], (double)le_w1[(d+3)*64+l], a3);
  }
  a = ((a0+a1)+(a2+a3)) + (double)le_b1[l];
  t1[l] = a > 0.0 ? a : 0.0;
  __syncthreads();
  // le2
  a0=a1=a2=a3=0.0;
  for (int d=0; d<64; d+=4){
    a0 = fma(t1[d  ], (double)le_w2[(d  )*64+l], a0);
    a1 = fma(t1[d+1], (double)le_w2[(d+1)*64+l], a1);
    a2 = fma(t1[d+2], (double)le_w2[(d+2)*64+l], a2);
    a3 = fma(t1[d+3], (double)le_w2[(d+3)*64+l], a3);
  }
  a = ((a0+a1)+(a2+a3)) + (double)le_b2[l];
  qe[l] = a;
  double sw = sqrt(log1p(exp((double)fw[l])) + 1e-9);
  double qv = a * sw;
  qwd[q*64+l] = qv;
  qwf[q*64+l] = (float)qv;
  double ss = wave_sum_d(qv*qv);
  if (l==0) qqd[q] = ss;
  // ge1 (128 wide): 2 outputs x 2 accs
  double b0=0,b1v=0,c0=0,c1=0;
  for (int d=0; d<64; d+=2){
    double x0 = xs[d], x1 = xs[d+1];
    b0  = fma(x0, (double)ge_w1[(d  )*128+l],    b0);
    b1v = fma(x1, (double)ge_w1[(d+1)*128+l],    b1v);
    c0  = fma(x0, (double)ge_w1[(d  )*128+64+l], c0);
    c1  = fma(x1, (double)ge_w1[(d+1)*128+64+l], c1);
  }
  a = (b0+b1v) + (double)ge_b1[l];
  double c = (c0+c1) + (double)ge_b1[64+l];
  h1[l] = a>0.0?a:0.0; h1[64+l] = c>0.0?c:0.0;
  __syncthreads();
  // ge2 (in 128)
  a0=a1=a2=a3=0.0;
  for (int d=0; d<128; d+=4){
    a0 = fma(h1[d  ], (double)ge_w2[(d  )*64+l], a0);
    a1 = fma(h1[d+1], (double)ge_w2[(d+1)*64+l], a1);
    a2 = fma(h1[d+2], (double)ge_w2[(d+2)*64+l], a2);
    a3 = fma(h1[d+3], (double)ge_w2[(d+3)*64+l], a3);
  }
  a = ((a0+a1)+(a2+a3)) + (double)ge_b2[l];
  __syncthreads();
  t1[l] = a>0.0?a:0.0;
  __syncthreads();
  // ge3
  a0=a1=a2=a3=0.0;
  for (int d=0; d<64; d+=4){
    a0 = fma(t1[d  ], (double)ge_w3[(d  )*64+l], a0);
    a1 = fma(t1[d+1], (double)ge_w3[(d+1)*64+l], a1);
    a2 = fma(t1[d+2], (double)ge_w3[(d+2)*64+l], a2);
    a3 = fma(t1[d+3], (double)ge_w3[(d+3)*64+l], a3);
  }
  a = ((a0+a1)+(a2+a3)) + (double)ge_b3[l];
  t2[l] = a;                // global_repr
  __syncthreads();
  // gr1
  a0=a1=a2=a3=0.0;
  for (int d=0; d<64; d+=4){
    a0 = fma(t2[d  ], (double)gr_w1[(d  )*64+l], a0);
    a1 = fma(t2[d+1], (double)gr_w1[(d+1)*64+l], a1);
    a2 = fma(t2[d+2], (double)gr_w1[(d+2)*64+l], a2);
    a3 = fma(t2[d+3], (double)gr_w1[(d+3)*64+l], a3);
  }
  a = ((a0+a1)+(a2+a3)) + (double)gr_b1[l];
  __syncthreads();
  t1[l] = a>0.0?a:0.0;
  __syncthreads();
  if (l < 8){
    a0=a1=a2=a3=0.0;
    for (int d=0; d<64; d+=4){
      a0 = fma(t1[d  ], (double)gr_w2[(d  )*8+l], a0);
      a1 = fma(t1[d+1], (double)gr_w2[(d+1)*8+l], a1);
      a2 = fma(t1[d+2], (double)gr_w2[(d+2)*8+l], a2);
      a3 = fma(t1[d+3], (double)gr_w2[(d+3)*8+l], a3);
    }
    gpd[q*8+l] = ((a0+a1)+(a2+a3)) + (double)gr_b2[l];
  }
  // gate
  a0=a1=a2=a3=0.0;
  for (int d=0; d<64; d+=4){
    a0 = fma(t2[d  ], (double)ga_w1[(d  )*64+l], a0);
    a1 = fma(t2[d+1], (double)ga_w1[(d+1)*64+l], a1);
    a2 = fma(t2[d+2], (double)ga_w1[(d+2)*64+l], a2);
    a3 = fma(t2[d+3], (double)ga_w1[(d+3)*64+l], a3);
  }
  for (int d=0; d<64; d+=4){
    a0 = fma(qe[d  ], (double)ga_w1[(64+d  )*64+l], a0);
    a1 = fma(qe[d+1], (double)ga_w1[(64+d+1)*64+l], a1);
    a2 = fma(qe[d+2], (double)ga_w1[(64+d+2)*64+l], a2);
    a3 = fma(qe[d+3], (double)ga_w1[(64+d+3)*64+l], a3);
  }
  a = ((a0+a1)+(a2+a3)) + (double)ga_b1[l];
  a = a>0.0?a:0.0;
  double p = wave_sum_d(a * (double)ga_w2[l]);
  if (l==0) ggd[q] = 1.0/(1.0 + exp(-(p + (double)ga_b2[0])));
}

// ---------------- K_tau: dump sample scores (j in [0,4096)) bit-identical to k3
__global__ __launch_bounds__(256) void k_tau(
    const float* __restrict__ mwT, const float* __restrict__ mm,
    const float* __restrict__ qw, float* __restrict__ ssc)
{
  int t = threadIdx.x, w = t>>6, lane = t&63;
  int q0 = blockIdx.x*32;
  int half = blockIdx.y;
  __shared__ float qs[2048];
  for (int i=t; i<2048; i+=256){
    int qrel = i>>6, d = i&63;
    qs[(qrel>>3)*512 + d*8 + (qrel&7)] = qw[q0*64 + i];
  }
  __syncthreads();
  for (int sub=0; sub<4; sub++){
    int jb = half*2048 + sub*512;
    float s[8][8];
    #pragma unroll
    for (int a=0;a<8;a++){
      #pragma unroll
      for (int b=0;b<8;b++) s[a][b]=0.f;
    }
    #pragma unroll 4
    for (int d=0; d<64; d++){
      const float* row = mwT + (size_t)d*NP + jb + 4*lane;
      float4 m0 = *(const float4*)row;
      float4 m1 = *(const float4*)(row + 256);
      const float* qp = qs + w*512 + d*8;
      float4 qA = *(const float4*)qp;
      float4 qB = *(const float4*)(qp+4);
      float qvv[8] = {qA.x,qA.y,qA.z,qA.w,qB.x,qB.y,qB.z,qB.w};
      float mvv[8] = {m0.x,m0.y,m0.z,m0.w,m1.x,m1.y,m1.z,m1.w};
      #pragma unroll
      for (int qi=0;qi<8;qi++){
        #pragma unroll
        for (int jj=0;jj<8;jj++) s[qi][jj] = fmaf(qvv[qi], mvv[jj], s[qi][jj]);
      }
    }
    float4 mmA = *(const float4*)(mm + jb + 4*lane);
    float4 mmB = *(const float4*)(mm + jb + 256 + 4*lane);
    float mmv[8] = {mmA.x,mmA.y,mmA.z,mmA.w,mmB.x,mmB.y,mmB.z,mmB.w};
    #pragma unroll
    for (int qi=0;qi<8;qi++){
      int qg = q0 + w*8 + qi;
      float4 o0, o1;
      o0.x = 2.f*s[qi][0]-mmv[0]; o0.y = 2.f*s[qi][1]-mmv[1];
      o0.z = 2.f*s[qi][2]-mmv[2]; o0.w = 2.f*s[qi][3]-mmv[3];
      o1.x = 2.f*s[qi][4]-mmv[4]; o1.y = 2.f*s[qi][5]-mmv[5];
      o1.z = 2.f*s[qi][6]-mmv[6]; o1.w = 2.f*s[qi][7]-mmv[7];
      *(float4*)(ssc + (size_t)qg*4096 + jb + 4*lane)       = o0;
      *(float4*)(ssc + (size_t)qg*4096 + jb + 256 + 4*lane) = o1;
    }
  }
}

// ---------------- K_tau_sel: exact 16th-largest of the 4096 sample scores per query
__global__ __launch_bounds__(256) void k_tau_sel(
    const float* __restrict__ ssc, float* __restrict__ tau)
{
  int t = threadIdx.x, w = t>>6, l = t&63, q = blockIdx.x;
  __shared__ unsigned su[4096];
  __shared__ int rs[4];
  const float* base = ssc + (size_t)q*4096;
  for (int i=t; i<4096; i+=256){
    unsigned f = __float_as_uint(base[i]);
    su[i] = f ^ ((f >> 31) ? 0xFFFFFFFFu : 0x80000000u);   // monotone key
  }
  __syncthreads();
  unsigned T = 0u;
  for (int b=31; b>=0; b--){
    unsigned cand = T | (1u<<b);
    int c = 0;
    for (int i=t; i<4096; i+=256) c += (su[i] >= cand) ? 1 : 0;
    c = wave_sum_i(c);
    if (l==0) rs[w] = c;
    __syncthreads();
    int tot = rs[0]+rs[1]+rs[2]+rs[3];
    if (tot >= 16) T = cand;
    __syncthreads();
  }
  if (t==0){
    unsigned f = (T & 0x80000000u) ? (T ^ 0x80000000u) : ~T;
    tau[q] = __uint_as_float(f);
  }
}

// ---------------- K3: all 98 j-blocks, filter >= tau - margin, append to buffer
__global__ __launch_bounds__(256) void k3_main(
    const float* __restrict__ mwT, const float* __restrict__ mm,
    const float* __restrict__ qw,  const float* __restrict__ tau,
    int* __restrict__ qcnt, float* __restrict__ qcv, int* __restrict__ qci)
{
  int t=threadIdx.x, w=t>>6, lane=t&63;
  int q0 = blockIdx.x*32;
  int c  = blockIdx.y;
  __shared__ float qs[2048];
  __shared__ float taus[32];
  for (int i=t; i<2048; i+=256){
    int qrel=i>>6, d=i&63;
    qs[(qrel>>3)*512 + d*8 + (qrel&7)] = qw[q0*64 + i];
  }
  if (t < 32){ taus[t] = tau[q0+t] - 5e-6f; }
  __syncthreads();
  for (int sub=0; sub<2; sub++){
    int jb = c*JBLK + sub*512;
    float s[8][8];
    #pragma unroll
    for (int a=0;a<8;a++){
      #pragma unroll
      for (int b=0;b<8;b++) s[a][b]=0.f;
    }
    #pragma unroll 4
    for (int d=0; d<64; d++){
      const float* row = mwT + (size_t)d*NP + jb + 4*lane;
      float4 m0 = *(const float4*)row;
      float4 m1 = *(const float4*)(row + 256);
      const float* qp = qs + w*512 + d*8;
      float4 qA = *(const float4*)qp;
      float4 qB = *(const float4*)(qp+4);
      float qvv[8] = {qA.x,qA.y,qA.z,qA.w,qB.x,qB.y,qB.z,qB.w};
      float mvv[8] = {m0.x,m0.y,m0.z,m0.w,m1.x,m1.y,m1.z,m1.w};
      #pragma unroll
      for (int qi=0;qi<8;qi++){
        #pragma unroll
        for (int jj=0;jj<8;jj++) s[qi][jj] = fmaf(qvv[qi], mvv[jj], s[qi][jj]);
      }
    }
    float4 mmA = *(const float4*)(mm + jb + 4*lane);
    float4 mmB = *(const float4*)(mm + jb + 256 + 4*lane);
    float mmv[8] = {mmA.x,mmA.y,mmA.z,mmA.w,mmB.x,mmB.y,mmB.z,mmB.w};
    #pragma unroll
    for (int qi=0;qi<8;qi++){
      float tq = taus[w*8+qi];
      int qg = q0 + w*8 + qi;
      #pragma unroll
      for (int jj=0;jj<8;jj++){
        float sc = 2.f*s[qi][jj] - mmv[jj];
        if (sc >= tq){
          int p = atomicAdd(&qcnt[qg], 1);
          if (p < QCAP){
            qcv[(size_t)qg*QCAP+p] = sc;
            qci[(size_t)qg*QCAP+p] = jb + ((jj<4)?(4*lane+jj):(256+4*lane+jj-4));
          }
        }
      }
    }
  }
}

// ---------------- K4: v16 (lane-max bitonic, safe-approx) -> threshold compaction ->
// multi-wave f64 re-rank -> f32-quantized select -> softmax/blend/refine
__global__ __launch_bounds__(256) void k4_final(
    const int* __restrict__ qcnt, const float* __restrict__ qcv, const int* __restrict__ qci,
    const double* __restrict__ qwd_g, const double* __restrict__ qqd_g,
    const double* __restrict__ ggd_g, const double* __restrict__ gpd_g,
    const float* __restrict__ mi, const float* __restrict__ mt,
    const float* __restrict__ le_w1, const float* __restrict__ le_b1,
    const float* __restrict__ le_w2, const float* __restrict__ le_b2,
    const float* __restrict__ fw, const float* __restrict__ itp,
    const float* __restrict__ rw1, const float* __restrict__ rb1,
    const float* __restrict__ rw2, const float* __restrict__ rb2,
    float* __restrict__ out)
{
  int t = threadIdx.x, w = t>>6, l = t&63, q = blockIdx.x;
  __shared__ float  svv[QCAP];
  __shared__ int    sii[QCAP];
  __shared__ float  v16s;
  __shared__ int    ncnt2;
  __shared__ int    candj[NCAND];
  __shared__ double cd2[NCAND];
  __shared__ double mdw[4][64], hdw[4][64];
  __shared__ float  selr[16];
  __shared__ int    selj[16];
  __shared__ double hh[32];
  int NC = qcnt[q]; NC = NC < QCAP ? NC : QCAP;
  // Phase A: load survivors
  for (int i=t; i<NC; i+=256){ svv[i]=qcv[(size_t)q*QCAP+i]; sii[i]=qci[(size_t)q*QCAP+i]; }
  if (t==0) ncnt2 = 0;
  __syncthreads();
  // Phase B (wave 0): v16m = 16th-largest of lane-maxes (<= exact 16th -> safe thr)
  if (t < 64){
    float vm = -3.0e38f;
    for (int i=l; i<NC; i+=64) vm = fmaxf(vm, svv[i]);
    vm = bitonic_sort64(vm, l);
    if (l == 48) v16s = vm;
  }
  __syncthreads();
  // Phase C: threshold compaction (order-independent final result)
  {
    float thr = v16s - 1e-5f;
    for (int i=t; i<NC; i+=256){
      if (svv[i] >= thr && (unsigned)sii[i] < (unsigned)N_MEM){
        int p = atomicAdd(&ncnt2, 1);
        if (p < NCAND) candj[p] = sii[i];
      }
    }
  }
  __syncthreads();
  int NC2 = ncnt2 < NCAND ? ncnt2 : NCAND;
  // Phase D: f64 re-rank, candidates distributed across the 4 waves
  double qwl = qwd_g[q*64+l];
  double swl = sqrt(log1p(exp((double)fw[l])) + 1e-9);
  double qq  = qqd_g[q];
  int CM = (NC2 + 3) >> 2;
  for (int it=0; it<CM; it++){
    int c = it*4 + w;
    bool act = (c < NC2);
    if (act){
      int j = candj[c];
      mdw[w][l] = (double)mi[(size_t)j*64 + l];
    }
    __syncthreads();
    if (act){
      double a0=0,a1=0,a2=0,a3=0;
      for (int d=0; d<64; d+=4){
        a0 = fma(mdw[w][d  ], (double)le_w1[(d  )*64+l], a0);
        a1 = fma(mdw[w][d+1], (double)le_w1[(d+1)*64+l], a1);
        a2 = fma(mdw[w][d+2], (double)le_w1[(d+2)*64+l], a2);
        a3 = fma(mdw[w][d+3], (double)le_w1[(d+3)*64+l], a3);
      }
      double h = (a0+a1)+(a2+a3) + (double)le_b1[l];
      hdw[w][l] = h>0.0 ? h : 0.0;
    }
    __syncthreads();
    if (act){
      double a0=0,a1=0,a2=0,a3=0;
      for (int d=0; d<64; d+=4){
        a0 = fma(hdw[w][d  ], (double)le_w2[(d  )*64+l], a0);
        a1 = fma(hdw[w][d+1], (double)le_w2[(d+1)*64+l], a1);
        a2 = fma(hdw[w][d+2], (double)le_w2[(d+2)*64+l], a2);
        a3 = fma(hdw[w][d+3], (double)le_w2[(d+3)*64+l], a3);
      }
      double o  = (a0+a1)+(a2+a3) + (double)le_b2[l];
      double mw = o * swl;
      double mm2 = wave_sum_d(mw*mw);
      double dt  = wave_sum_d(mw*qwl);
      if (l==0) cd2[c] = qq + mm2 - 2.0*dt;
    }
    __syncthreads();
  }
  // Phase E (wave 0): f32-quantized raw + top-16 by (raw32 desc, idx asc); 2 slots/lane
  if (t < 64){
    float e32  = (float)exp((double)itp[0]);
    float sp32 = (float)log1p((double)e32);
    float t32  = __fadd_rn(sp32, 1e-9f);      // temp = softplus + EPS
    float dn32 = __fadd_rn(t32, 1e-9f);       // denom = temp + EPS
    double denom = (double)dn32;
    float r0=-2.f, r1=-2.f; int j0=0x7fffffff, j1=0x7fffffff;
    if (l < NC2){
      double d2 = cd2[l]; if (d2 < 0.0) d2 = 0.0;
      float ratio32 = (float)(d2 / denom);
      r0 = (float)exp(-(double)ratio32);
      j0 = candj[l];
    }
    if (l+64 < NC2){
      double d2 = cd2[l+64]; if (d2 < 0.0) d2 = 0.0;
      float ratio32 = (float)(d2 / denom);
      r1 = (float)exp(-(double)ratio32);
      j1 = candj[l+64];
    }
    bool u0=false, u1=false;
    for (int it=0; it<16; it++){
      float a0 = u0 ? -2.f : r0;
      float a1 = u1 ? -2.f : r1;
      float v; int j; int p;
      if (a0 > a1 || (a0 == a1 && j0 <= j1)) { v=a0; j=j0; p=l*2; }
      else                                   { v=a1; j=j1; p=l*2+1; }
      wave_argmax3(v, j, p);
      if ((p>>1) == l){ if (p&1) u1=true; else u0=true; }
      if (l == it){ selr[it]=v; selj[it]=j; }
    }
  }
  __syncthreads();
  // Phase F (wave 0): f64 softmax over quantized raws, gather, blend, refine
  if (t < 64){
    double raw = (l<16) ? (double)selr[l] : -1.0e300;
    double mv = raw;
    #pragma unroll
    for (int o=32;o;o>>=1){ double ov = __shfl_xor(mv,o,64); mv = ov>mv?ov:mv; }
    double e  = (l<16) ? exp(raw - mv) : 0.0;
    double se = wave_sum_d(e);
    double wgt = e / se;
    double lp[8] = {0,0,0,0,0,0,0,0};
    if (l < 16){
      const float* tr = mt + (size_t)selj[l]*8;
      #pragma unroll
      for (int tt=0; tt<8; tt++) lp[tt] = wgt * (double)tr[tt];
    }
    #pragma unroll
    for (int tt=0; tt<8; tt++) lp[tt] = wave_sum_d(lp[tt]);
    double g = ggd_g[q];
    double bl[8];
    #pragma unroll
    for (int tt=0; tt<8; tt++) bl[tt] = g*lp[tt] + (1.0-g)*gpd_g[q*8+tt];
    if (l < 32){
      double a = (double)rb1[l];
      #pragma unroll
      for (int tt=0; tt<8; tt++) a = fma(bl[tt], (double)rw1[tt*32+l], a);
      hh[l] = a>0.0?a:0.0;
    }
  }
  __syncthreads();
  if (t < 8){
    double a = (double)rb2[t];
    #pragma unroll
    for (int i=0; i<32; i++) a = fma(hh[i], (double)rw2[i*8+t], a);
    out[q*8+t] = (float)a;
  }
}

extern "C" void kernel_launch(void* const* d_in, const int* in_sizes, int n_in,
                              void* d_out, int out_size, void* d_ws, size_t ws_size,
                              hipStream_t stream)
{
  const float* x     = (const float*)d_in[0];
  const float* mi    = (const float*)d_in[1];
  const float* mt    = (const float*)d_in[2];
  const float* le_w1 = (const float*)d_in[3];
  const float* le_b1 = (const float*)d_in[4];
  const float* le_w2 = (const float*)d_in[5];
  const float* le_b2 = (const float*)d_in[6];
  const float* fw    = (const float*)d_in[7];
  const float* itp   = (const float*)d_in[8];
  const float* ge_w1 = (const float*)d_in[9];
  const float* ge_b1 = (const float*)d_in[10];
  const float* ge_w2 = (const float*)d_in[11];
  const float* ge_b2 = (const float*)d_in[12];
  const float* ge_w3 = (const float*)d_in[13];
  const float* ge_b3 = (const float*)d_in[14];
  const float* gr_w1 = (const float*)d_in[15];
  const float* gr_b1 = (const float*)d_in[16];
  const float* gr_w2 = (const float*)d_in[17];
  const float* gr_b2 = (const float*)d_in[18];
  const float* ga_w1 = (const float*)d_in[19];
  const float* ga_b1 = (const float*)d_in[20];
  const float* ga_w2 = (const float*)d_in[21];
  const float* ga_b2 = (const float*)d_in[22];
  const float* rh_w1 = (const float*)d_in[23];
  const float* rh_b1 = (const float*)d_in[24];
  const float* rh_w2 = (const float*)d_in[25];
  const float* rh_b2 = (const float*)d_in[26];

  // doubles first (8B alignment), then float/int region
  double* dws = (double*)d_ws;
  double* qwd = dws;                                // 1024*64
  double* qqd = qwd + (size_t)1024*64;              // 1024
  double* ggd = qqd + 1024;                         // 1024
  double* gpd = ggd + 1024;                         // 8192
  float*  fws = (float*)(gpd + 8192);
  float* mwT = fws;                                 // 64*NP
  float* mm  = mwT + (size_t)64*NP;                 // NP
  float* qwf = mm  + NP;                            // 1024*64
  float* tau = qwf + (size_t)1024*64;               // 1024
  float* ssc = tau + 1024;                          // 1024*4096
  int*   qcnt= (int*)(ssc + (size_t)1024*4096);     // 1024
  float* qcv = (float*)(qcnt + 1024);               // 1024*QCAP
  int*   qci = (int*)(qcv + (size_t)1024*QCAP);     // 1024*QCAP

  k1_mem    <<<dim3(NP/128), dim3(128), 0, stream>>>(mi, le_w1, le_b1, le_w2, le_b2, fw, mwT, mm);
  k2_query  <<<dim3(1024),   dim3(64),  0, stream>>>(x, le_w1, le_b1, le_w2, le_b2, fw,
                ge_w1, ge_b1, ge_w2, ge_b2, ge_w3, ge_b3,
                gr_w1, gr_b1, gr_w2, gr_b2,
                ga_w1, ga_b1, ga_w2, ga_b2,
                qwf, qwd, qqd, ggd, gpd, qcnt);
  k_tau     <<<dim3(32,2),   dim3(256), 0, stream>>>(mwT, mm, qwf, ssc);
  k_tau_sel <<<dim3(1024),   dim3(256), 0, stream>>>(ssc, tau);
  k3_main   <<<dim3(32,NJB), dim3(256), 0, stream>>>(mwT, mm, qwf, tau, qcnt, qcv, qci);
  k4_final  <<<dim3(1024),   dim3(256), 0, stream>>>(qcnt, qcv, qci, qwd, qqd, ggd, gpd, mi, mt,
                le_w1, le_b1, le_w2, le_b2, fw, itp,
                rh_w1, rh_b1, rh_w2, rh_b2, (float*)d_out);
}